// Round 2
// baseline (699.812 us; speedup 1.0000x reference)
//
#include <hip/hip_runtime.h>
#include <cmath>

#define NLEV 8
#define TSZ 16384
#define PRIME 2654435761u

struct Res { int rx[NLEV]; int ry[NLEV]; };

__global__ __launch_bounds__(256) void pg_kernel(
    const float* __restrict__ x,
    const int*   __restrict__ hashidxs,
    const float* __restrict__ table,
    const float* __restrict__ w1,   // 16x32
    const float* __restrict__ b1,   // 32
    const float* __restrict__ w2,   // 32x24
    const float* __restrict__ b2,   // 24
    float* __restrict__ out,        // [mu N*8 | inv_sigma N*8 | weight N*8 | H N*16]
    int N, Res res)
{
    int i = blockIdx.x * blockDim.x + threadIdx.x;
    if (i >= N) return;

    float2 xv = ((const float2*)x)[i];
    int hv = hashidxs[i];
    const float2* tb2 = (const float2*)table;
    unsigned base0 = (unsigned)hv * (NLEV * TSZ);

    // ---- Phase 1: compute all 32 gather addresses and ISSUE ALL LOADS ----
    // Holding f[8][4] (64 VGPRs) keeps all 32 global loads in flight at once:
    // one miss-latency round instead of eight (R1 showed VGPR=44 => compiler
    // had serialized levels; latency-bound at 39% VALUBusy / 45% HBM).
    float wx[NLEV], wy[NLEV];
    float2 f[NLEV][4];
    #pragma unroll
    for (int l = 0; l < NLEV; ++l) {
        float posx = xv.x * (float)res.rx[l];
        float posy = xv.y * (float)res.ry[l];
        float p0x = floorf(posx), p0y = floorf(posy);
        wx[l] = posx - p0x;
        wy[l] = posy - p0y;
        unsigned cx = (unsigned)p0x, cy = (unsigned)p0y;
        unsigned hy0 = cy * PRIME;
        unsigned hy1 = (cy + 1u) * PRIME;
        unsigned b = base0 + (unsigned)l * TSZ;
        f[l][0] = tb2[b + (( cx       ^ hy0) & (TSZ - 1))];
        f[l][1] = tb2[b + (((cx + 1u) ^ hy0) & (TSZ - 1))];
        f[l][2] = tb2[b + (( cx       ^ hy1) & (TSZ - 1))];
        f[l][3] = tb2[b + (((cx + 1u) ^ hy1) & (TSZ - 1))];
    }

    // ---- Phase 2: bilinear blend (consumes the loads) ----
    float H[16];
    #pragma unroll
    for (int l = 0; l < NLEV; ++l) {
        float w00 = (1.f - wx[l]) * (1.f - wy[l]);
        float w10 = wx[l] * (1.f - wy[l]);
        float w01 = (1.f - wx[l]) * wy[l];
        float w11 = wx[l] * wy[l];
        H[2*l]   = fmaf(f[l][0].x, w00, fmaf(f[l][1].x, w10, fmaf(f[l][2].x, w01, f[l][3].x * w11)));
        H[2*l+1] = fmaf(f[l][0].y, w00, fmaf(f[l][1].y, w10, fmaf(f[l][2].y, w01, f[l][3].y * w11)));
    }

    // ---- layer 1: 16 -> 32, gaussian activation exp(-50*s^2) ----
    float h1[32];
    #pragma unroll
    for (int j = 0; j < 32; ++j) {
        float s = b1[j];
        #pragma unroll
        for (int k = 0; k < 16; ++k) s = fmaf(H[k], w1[k * 32 + j], s);
        h1[j] = __expf(-50.f * s * s);
    }

    // ---- layer 2: 32 -> 24 ----
    float raw[24];
    #pragma unroll
    for (int j = 0; j < 24; ++j) {
        float s = b2[j];
        #pragma unroll
        for (int k = 0; k < 32; ++k) s = fmaf(h1[k], w2[k * 24 + j], s);
        raw[j] = s;
    }

    // ---- heads ----
    float wt[8], mu[8], isg[8];
    #pragma unroll
    for (int g = 0; g < 8; ++g) {
        wt[g]  = __expf(raw[g]);
        mu[g]  = 1.f / (1.f + __expf(-raw[8 + g]));
        isg[g] = __expf(raw[16 + g]);
    }

    size_t N8 = (size_t)N * 8;
    float4* o;
    o = (float4*)(out) + (size_t)i * 2;
    o[0] = make_float4(mu[0], mu[1], mu[2], mu[3]);
    o[1] = make_float4(mu[4], mu[5], mu[6], mu[7]);
    o = (float4*)(out + N8) + (size_t)i * 2;
    o[0] = make_float4(isg[0], isg[1], isg[2], isg[3]);
    o[1] = make_float4(isg[4], isg[5], isg[6], isg[7]);
    o = (float4*)(out + 2 * N8) + (size_t)i * 2;
    o[0] = make_float4(wt[0], wt[1], wt[2], wt[3]);
    o[1] = make_float4(wt[4], wt[5], wt[6], wt[7]);
    o = (float4*)(out + 3 * N8) + (size_t)i * 4;
    o[0] = make_float4(H[0],  H[1],  H[2],  H[3]);
    o[1] = make_float4(H[4],  H[5],  H[6],  H[7]);
    o[2] = make_float4(H[8],  H[9],  H[10], H[11]);
    o[3] = make_float4(H[12], H[13], H[14], H[15]);
}

extern "C" void kernel_launch(void* const* d_in, const int* in_sizes, int n_in,
                              void* d_out, int out_size, void* d_ws, size_t ws_size,
                              hipStream_t stream) {
    const float* x        = (const float*)d_in[0];
    const int*   hashidxs = (const int*)  d_in[1];
    // d_in[2] = color (unused by reference computation)
    const float* table    = (const float*)d_in[3];
    const float* w1       = (const float*)d_in[4];
    const float* b1       = (const float*)d_in[5];
    const float* w2       = (const float*)d_in[6];
    const float* b2       = (const float*)d_in[7];
    float* out = (float*)d_out;
    int N = in_sizes[0] / 2;

    // Replicate numpy's _level_resolutions() double-precision op sequence
    // exactly (log/exp/pow via libm) — floor(16*bx^7) sits ~3e-15 from 1024,
    // so hardcoding a guess risks an off-by-one at the finest level.
    Res res;
    double bx = std::exp((std::log((double)1024) - std::log((double)16)) / 7.0);
    double by = std::exp((std::log((double)768)  - std::log((double)16)) / 7.0);
    for (int l = 0; l < NLEV; ++l) {
        res.rx[l] = (int)std::floor(16.0 * std::pow(bx, (double)l));
        res.ry[l] = (int)std::floor(16.0 * std::pow(by, (double)l));
    }

    dim3 block(256), grid((unsigned)((N + 255) / 256));
    hipLaunchKernelGGL(pg_kernel, grid, block, 0, stream,
                       x, hashidxs, table, w1, b1, w2, b2, out, N, res);
}

// Round 3
// 687.391 us; speedup vs baseline: 1.0181x; 1.0181x over previous
//
#include <hip/hip_runtime.h>
#include <cmath>

#define NLEV 8
#define TSZ 16384
#define PRIME 2654435761u

struct Res { int rx[NLEV]; int ry[NLEV]; };

typedef float v2f __attribute__((ext_vector_type(2)));
typedef float v4f __attribute__((ext_vector_type(4)));

__global__ __launch_bounds__(256) void pg_kernel(
    const float* __restrict__ x,
    const int*   __restrict__ hashidxs,
    const float* __restrict__ table,
    const float* __restrict__ w1,   // 16x32
    const float* __restrict__ b1,   // 32
    const float* __restrict__ w2,   // 32x24
    const float* __restrict__ b2,   // 24
    float* __restrict__ out,        // [mu N*8 | inv_sigma N*8 | weight N*8 | H N*16]
    int N, Res res)
{
    int i = blockIdx.x * blockDim.x + threadIdx.x;
    if (i >= N) return;

    v2f xv = __builtin_nontemporal_load((const v2f*)x + i);
    int hv = __builtin_nontemporal_load(hashidxs + i);
    const v2f* tb2 = (const v2f*)table;
    unsigned base0 = (unsigned)hv * (NLEV * TSZ);

    // ---- Phase 1: issue ALL 32 gathers via asm volatile (scheduler cannot
    // sink/interleave these; R1/R2 showed VGPR=44 => compiler serialized the
    // levels into 8 sequential miss-latency rounds). One vmcnt(0) total.
    float wx[NLEV], wy[NLEV];
    v2f f[NLEV][4];
    #pragma unroll
    for (int l = 0; l < NLEV; ++l) {
        float posx = xv.x * (float)res.rx[l];
        float posy = xv.y * (float)res.ry[l];
        float p0x = floorf(posx), p0y = floorf(posy);
        wx[l] = posx - p0x;
        wy[l] = posy - p0y;
        unsigned cx = (unsigned)p0x, cy = (unsigned)p0y;
        unsigned hy0 = cy * PRIME;
        unsigned hy1 = (cy + 1u) * PRIME;
        unsigned b = base0 + (unsigned)l * TSZ;
        const v2f* p00 = tb2 + (b + (( cx       ^ hy0) & (TSZ - 1)));
        const v2f* p10 = tb2 + (b + (((cx + 1u) ^ hy0) & (TSZ - 1)));
        const v2f* p01 = tb2 + (b + (( cx       ^ hy1) & (TSZ - 1)));
        const v2f* p11 = tb2 + (b + (((cx + 1u) ^ hy1) & (TSZ - 1)));
        asm volatile("global_load_dwordx2 %0, %1, off" : "=v"(f[l][0]) : "v"(p00));
        asm volatile("global_load_dwordx2 %0, %1, off" : "=v"(f[l][1]) : "v"(p10));
        asm volatile("global_load_dwordx2 %0, %1, off" : "=v"(f[l][2]) : "v"(p01));
        asm volatile("global_load_dwordx2 %0, %1, off" : "=v"(f[l][3]) : "v"(p11));
    }
    // Wait once for all 32, then fence each value so the blend cannot be
    // hoisted above the wait (volatile asms stay in program order).
    asm volatile("s_waitcnt vmcnt(0)" ::: "memory");
    #pragma unroll
    for (int l = 0; l < NLEV; ++l)
        asm volatile("" : "+v"(f[l][0]), "+v"(f[l][1]), "+v"(f[l][2]), "+v"(f[l][3]));

    // ---- Phase 2: bilinear blend ----
    float H[16];
    #pragma unroll
    for (int l = 0; l < NLEV; ++l) {
        float w00 = (1.f - wx[l]) * (1.f - wy[l]);
        float w10 = wx[l] * (1.f - wy[l]);
        float w01 = (1.f - wx[l]) * wy[l];
        float w11 = wx[l] * wy[l];
        H[2*l]   = fmaf(f[l][0].x, w00, fmaf(f[l][1].x, w10, fmaf(f[l][2].x, w01, f[l][3].x * w11)));
        H[2*l+1] = fmaf(f[l][0].y, w00, fmaf(f[l][1].y, w10, fmaf(f[l][2].y, w01, f[l][3].y * w11)));
    }

    // ---- layer 1: 16 -> 32, gaussian activation exp(-50*s^2) ----
    float h1[32];
    #pragma unroll
    for (int j = 0; j < 32; ++j) {
        float s = b1[j];
        #pragma unroll
        for (int k = 0; k < 16; ++k) s = fmaf(H[k], w1[k * 32 + j], s);
        h1[j] = __expf(-50.f * s * s);
    }

    // ---- layer 2: 32 -> 24 ----
    float raw[24];
    #pragma unroll
    for (int j = 0; j < 24; ++j) {
        float s = b2[j];
        #pragma unroll
        for (int k = 0; k < 32; ++k) s = fmaf(h1[k], w2[k * 24 + j], s);
        raw[j] = s;
    }

    // ---- heads ----
    float wt[8], mu[8], isg[8];
    #pragma unroll
    for (int g = 0; g < 8; ++g) {
        wt[g]  = __expf(raw[g]);
        mu[g]  = 1.f / (1.f + __expf(-raw[8 + g]));
        isg[g] = __expf(raw[16 + g]);
    }

    // ---- streaming stores: non-temporal so 335 MB of out traffic doesn't
    // evict the hash table from L2 (gathers are the L2-sensitive traffic).
    size_t N8 = (size_t)N * 8;
    v4f* o;
    v4f t0, t1;
    o = (v4f*)(out) + (size_t)i * 2;
    t0 = v4f{mu[0], mu[1], mu[2], mu[3]};
    t1 = v4f{mu[4], mu[5], mu[6], mu[7]};
    __builtin_nontemporal_store(t0, o);
    __builtin_nontemporal_store(t1, o + 1);
    o = (v4f*)(out + N8) + (size_t)i * 2;
    t0 = v4f{isg[0], isg[1], isg[2], isg[3]};
    t1 = v4f{isg[4], isg[5], isg[6], isg[7]};
    __builtin_nontemporal_store(t0, o);
    __builtin_nontemporal_store(t1, o + 1);
    o = (v4f*)(out + 2 * N8) + (size_t)i * 2;
    t0 = v4f{wt[0], wt[1], wt[2], wt[3]};
    t1 = v4f{wt[4], wt[5], wt[6], wt[7]};
    __builtin_nontemporal_store(t0, o);
    __builtin_nontemporal_store(t1, o + 1);
    o = (v4f*)(out + 3 * N8) + (size_t)i * 4;
    t0 = v4f{H[0],  H[1],  H[2],  H[3]};
    t1 = v4f{H[4],  H[5],  H[6],  H[7]};
    __builtin_nontemporal_store(t0, o);
    __builtin_nontemporal_store(t1, o + 1);
    t0 = v4f{H[8],  H[9],  H[10], H[11]};
    t1 = v4f{H[12], H[13], H[14], H[15]};
    __builtin_nontemporal_store(t0, o + 2);
    __builtin_nontemporal_store(t1, o + 3);
}

extern "C" void kernel_launch(void* const* d_in, const int* in_sizes, int n_in,
                              void* d_out, int out_size, void* d_ws, size_t ws_size,
                              hipStream_t stream) {
    const float* x        = (const float*)d_in[0];
    const int*   hashidxs = (const int*)  d_in[1];
    // d_in[2] = color (unused by reference computation)
    const float* table    = (const float*)d_in[3];
    const float* w1       = (const float*)d_in[4];
    const float* b1       = (const float*)d_in[5];
    const float* w2       = (const float*)d_in[6];
    const float* b2       = (const float*)d_in[7];
    float* out = (float*)d_out;
    int N = in_sizes[0] / 2;

    // Replicate numpy's _level_resolutions() double-precision op sequence
    // exactly (log/exp/pow via libm) — floor(16*bx^7) sits ~3e-15 from 1024,
    // so hardcoding a guess risks an off-by-one at the finest level.
    Res res;
    double bx = std::exp((std::log((double)1024) - std::log((double)16)) / 7.0);
    double by = std::exp((std::log((double)768)  - std::log((double)16)) / 7.0);
    for (int l = 0; l < NLEV; ++l) {
        res.rx[l] = (int)std::floor(16.0 * std::pow(bx, (double)l));
        res.ry[l] = (int)std::floor(16.0 * std::pow(by, (double)l));
    }

    dim3 block(256), grid((unsigned)((N + 255) / 256));
    hipLaunchKernelGGL(pg_kernel, grid, block, 0, stream,
                       x, hashidxs, table, w1, b1, w2, b2, out, N, res);
}